// Round 5
// baseline (1365.840 us; speedup 1.0000x reference)
//
#include <hip/hip_runtime.h>

// Problem constants
#define A_N   512
#define E_DIM 64
#define H_DIM 128
#define K_CAT 320         // E + soc(128) + h(128)
#define T_OBS 8
#define PRED  12
#define NBLK  512
#define NTHR  256

typedef __attribute__((ext_vector_type(8))) short bf16x8;
typedef __attribute__((ext_vector_type(4))) float f32x4;
typedef __attribute__((ext_vector_type(4))) unsigned uint4v;
#define MFMA16(a,b,c) __builtin_amdgcn_mfma_f32_16x16x32_bf16((a),(b),(c),0,0,0)
#define AS __ATOMIC_RELAXED, __HIP_MEMORY_SCOPE_AGENT

// workspace offsets (bytes)
#define WP_OFF   0           // 128*8192*2 = 2097152
#define WZ_OFF   2097152     // 512*320*2  = 327680
#define BZ_OFF   2424832     // 512*4
#define MASK_OFF 2426880     // 512*4
#define CUR_OFF  2428928     // 512*2*4
#define HG_OFF   2433024     // 512*128*2  = 131072
#define U_OFF    2564096     // 512*64*128*2 = 8388608
#define BAR_OFF  10952704    // 2048*4

// ---- coherent (cross-XCD) access helpers: relaxed agent atomics, NO fences ---
static __device__ __forceinline__ void st32c(void* p, unsigned v){
    __hip_atomic_store((unsigned*)p, v, AS);
}
static __device__ __forceinline__ void st64c(void* p, unsigned long long v){
    __hip_atomic_store((unsigned long long*)p, v, AS);
}
static __device__ __forceinline__ unsigned ld32c(const void* p){
    return __hip_atomic_load((const unsigned*)p, AS);
}
static __device__ __forceinline__ unsigned long long ld64c(const void* p){
    return __hip_atomic_load((const unsigned long long*)p, AS);
}
static __device__ __forceinline__ bf16x8 ldfragc(const unsigned short* p){
    union { unsigned long long q[2]; bf16x8 v; } u;
    u.q[0] = ld64c(p); u.q[1] = ld64c(p + 4);
    return u.v;
}

static __device__ __forceinline__ unsigned short f2bf(float x){
    union { float f; unsigned u; } v; v.f = x;
    unsigned r = v.u + 0x7fffu + ((v.u >> 16) & 1u);   // RNE
    return (unsigned short)(r >> 16);
}
static __device__ __forceinline__ unsigned pack2(float a, float b){
    return (unsigned)f2bf(a) | ((unsigned)f2bf(b) << 16);
}
static __device__ __forceinline__ float bf2lo(unsigned v){ return __uint_as_float(v << 16); }
static __device__ __forceinline__ float bf2hi(unsigned v){ return __uint_as_float(v & 0xffff0000u); }
static __device__ __forceinline__ float sigm_f(float x){ return 1.f / (1.f + __expf(-x)); }
static __device__ __forceinline__ float tanh_f(float x){
    float e = __expf(-2.f * fabsf(x));
    float t = (1.f - e) / (1.f + e);
    return copysignf(t, x);
}

// grid barrier: monotonic relaxed counters only — no fences, no cache flushes.
static __device__ __forceinline__ void gridbar(int* bar, int bid, int& gen){
    __syncthreads();
    if (threadIdx.x == 0){
        asm volatile("s_waitcnt vmcnt(0) lgkmcnt(0)" ::: "memory");
        gen++;
        int p = __hip_atomic_fetch_add(&bar[32 + (bid >> 3)*16], 1, AS);
        if ((p & 7) == 7){
            int q = __hip_atomic_fetch_add(&bar[16], 1, AS);
            if ((q & 63) == 63)
                __hip_atomic_store(&bar[0], gen, AS);
        }
        int spins = 0;
        while (__hip_atomic_load(&bar[0], AS) < gen){
            __builtin_amdgcn_s_sleep(2);
            if (++spins > (1 << 22)) break;   // safety bail: no hang
        }
        asm volatile("" ::: "memory");
    }
    __syncthreads();
}

__global__ void bar_init(int* bar){
    int i = blockIdx.x * 1024 + threadIdx.x;
    if (i < 2048) bar[i] = 0;
}

struct SP1 { unsigned short ustage[64][256]; };   // 32 KB
struct SP2 {
    float2 pos[A_N];          // 4096
    short  cell[A_N];         // 1024
    short  list[A_N];         // 1024
    int    nvalid;
    float  socp[8][128];      // 4096
    float  x[K_CAT];          // 1280
    float  zpart[2][512];     // 4096
    float  hrow[H_DIM];       // 512
};
union Smem { SP1 p1; SP2 p2; };

__global__ __launch_bounds__(NTHR, 2) void social_persist(
    const float* __restrict__ obs, const unsigned char* __restrict__ mraw,
    const float* __restrict__ W_e, const float* __restrict__ b_e,
    const float* __restrict__ Wp,  const float* __restrict__ b_p,
    const float* __restrict__ Wih, const float* __restrict__ Whh,
    const float* __restrict__ bih, const float* __restrict__ bhh,
    const float* __restrict__ W_o, const float* __restrict__ b_o,
    unsigned short* wp_bf, unsigned short* wz, float* bz, int* mski,
    float* cur, unsigned short* hglob, unsigned short* U,
    int* bar, float* out)
{
    __shared__ Smem sm;
    __shared__ int mflagA, mflagB;
    const int bid = blockIdx.x, tid = threadIdx.x;
    int gen = 0;
    // persistent per-agent state (block bid owns agent bid forever)
    float c_reg = 0.f;     // cell state for unit `tid` (valid tid<128)
    float h_reg = 0.f;     // hidden state for unit `tid` (valid tid<128)
    float cx_r = 0.f, cy_r = 0.f;   // cur position (valid tid==0)

    // ---------------- prep: weights -> bf16 (coherent stores), init ----------
    {
        const int i0 = bid * NTHR + tid, stride = NBLK * NTHR;     // 131072
        for (int i = i0; i < 524288; i += stride)                  // W_p pairs
            st32c((unsigned*)wp_bf + i, pack2(Wp[2*i], Wp[2*i + 1]));
        for (int i = i0; i < 81920; i += stride){                  // W_z pairs
            int n = (2*i) / K_CAT, k = (2*i) - n*K_CAT;
            float w0 = (k < 192)     ? Wih[n*192 + k]     : Whh[n*128 + k - 192];
            float w1 = (k + 1 < 192) ? Wih[n*192 + k + 1] : Whh[n*128 + k + 1 - 192];
            st32c((unsigned*)wz + i, pack2(w0, w1));
        }
        for (int i = i0; i < 512; i += stride)
            st32c((unsigned*)bz + i, __float_as_uint(bih[i] + bhh[i]));
        for (int i = i0; i < 16384; i += stride)                   // hglob = 0
            st64c((unsigned long long*)hglob + i, 0ull);
        if (bid == 0){
            if (tid == 0){ mflagA = 0; mflagB = 0; }
            __syncthreads();
            for (int j = tid; j < 512; j += NTHR){
                unsigned char b = mraw[j];
                if (b && (j & 3))        atomicAdd(&mflagA, 1);
                if (b && ((j & 7) == 4)) atomicAdd(&mflagB, 1);
            }
            __syncthreads();
            for (int j = tid; j < 512; j += NTHR){
                int v;
                if (mflagA)      v = mraw[j] ? 1 : 0;
                else if (mflagB) v = ((const int*)mraw)[j] ? 1 : 0;
                else             v = ((const long long*)mraw)[j] ? 1 : 0;
                st32c(mski + j, (unsigned)v);
            }
        }
    }
    gridbar(bar, bid, gen);

    for (int t = 0; t < T_OBS + PRED; ++t){
        // ============ P1: U-GEMM  U[j][c][:] = W_c · h[j]  (256 blocks) ======
        if (bid < 256){
            const int cq = bid >> 3, m0 = (bid & 7) * 64;
            const int w = tid >> 6, lane = tid & 63;
            const int lrow = lane & 15, lk = (lane >> 4) * 8;
            const unsigned short* ar = hglob + (m0 + w*16 + lrow)*128 + lk;
            bf16x8 a0 = ldfragc(ar);
            bf16x8 a1 = ldfragc(ar + 32);
            bf16x8 a2 = ldfragc(ar + 64);
            bf16x8 a3 = ldfragc(ar + 96);
            f32x4 acc[16] = {};
            #pragma unroll
            for (int cl = 0; cl < 2; ++cl){
                const unsigned short* bb = wp_bf + lrow*8192 + (2*cq + cl)*128 + lk;
                #pragma unroll
                for (int nt = 0; nt < 8; ++nt){
                    const unsigned short* bp = bb + nt*16*8192;
                    int ai = cl*8 + nt;
                    acc[ai] = MFMA16(a0, *(const bf16x8*)(bp      ), acc[ai]);
                    acc[ai] = MFMA16(a1, *(const bf16x8*)(bp + 32 ), acc[ai]);
                    acc[ai] = MFMA16(a2, *(const bf16x8*)(bp + 64 ), acc[ai]);
                    acc[ai] = MFMA16(a3, *(const bf16x8*)(bp + 96 ), acc[ai]);
                }
            }
            const int crow = (lane >> 4) * 4, ccol = lane & 15;
            #pragma unroll
            for (int ai = 0; ai < 16; ++ai){
                int colb = (ai >> 3)*128 + (ai & 7)*16 + ccol;
                #pragma unroll
                for (int r = 0; r < 4; ++r)
                    sm.p1.ustage[w*16 + crow + r][colb] = f2bf(acc[ai][r]);
            }
            __syncthreads();
            for (int e = tid; e < 4096; e += NTHR){
                int r = e >> 6, o = e & 63;
                unsigned long long v = *(const unsigned long long*)&sm.p1.ustage[r][o*4];
                st64c((unsigned long long*)U + ((m0 + r)*64 + 2*cq)*32 + o, v);
            }
        }
        gridbar(bar, bid, gen);

        // ============ P2: pos/cells/gather + LSTM + head (agent = bid) =======
        {
            SP2& s2 = sm.p2;
            const int mode = (t < T_OBS) ? 0 : ((t == T_OBS) ? 1 : 2);
            if (mode == 2){
                for (int j = tid; j < A_N; j += NTHR){
                    union { float f[2]; unsigned long long q; } cu;
                    cu.q = ld64c((const unsigned long long*)cur + j);
                    s2.pos[j] = make_float2(cu.f[0], cu.f[1]);
                }
            } else {
                int tt = (mode == 0) ? t : (T_OBS - 1);
                for (int j = tid; j < A_N; j += NTHR){
                    float px = obs[tt*1024 + 2*j], py = obs[tt*1024 + 2*j + 1];
                    if (isnan(px)) px = 0.f;
                    if (isnan(py)) py = 0.f;
                    if (mode == 1 && !mski[j]){ px = 0.f; py = 0.f; }
                    s2.pos[j] = make_float2(px, py);
                }
            }
            __syncthreads();
            const float2 pi = s2.pos[bid];
            const int vi = mski[bid];
            for (int j = tid; j < A_N; j += NTHR){
                int cc = -1;
                if (vi && j != bid && mski[j]){
                    float rx = s2.pos[j].x - pi.x, ry = s2.pos[j].y - pi.y;
                    if (fabsf(rx) < 32.f && fabsf(ry) < 32.f){
                        int col = (int)floorf((rx + 32.f) * 0.125f);
                        int row = (int)floorf((ry + 32.f) * 0.125f);
                        col = min(max(col, 0), 7); row = min(max(row, 0), 7);
                        cc = row*8 + col;
                    }
                }
                s2.cell[j] = (short)cc;
            }
            __syncthreads();
            // compaction (wave 0) || x-prefill (emb by tids 128-191, h by tids<128)
            if (tid < 64){
                int base = 0;
                for (int b = 0; b < 8; ++b){
                    short cj = s2.cell[b*64 + tid];
                    bool val = cj >= 0;
                    unsigned long long bal = __ballot(val);
                    int pre = __popcll(bal & ((1ull << tid) - 1ull));
                    if (val) s2.list[base + pre] = (short)((b*64 + tid) | ((int)cj << 9));
                    base += __popcll(bal);
                }
                if (tid == 0) s2.nvalid = base;
            } else if (tid < 128){
                s2.x[192 + tid] = h_reg;   // wait: only valid for tid<128; tids 64-127 write their h
            } else if (tid < 192){
                int u = tid - 128;
                float e = W_e[u*2]*pi.x + W_e[u*2 + 1]*pi.y + b_e[u];
                s2.x[u] = fmaxf(e, 0.f);
            }
            if (tid < 64) s2.x[192 + tid] = h_reg;   // tids 0-63 after compaction
            __syncthreads();
            const int nv = s2.nvalid;
            // gather: 8 entries per block-iteration (4 waves x 2 half-waves, 8B/lane)
            const int w = tid >> 6, lh = (tid >> 5) & 1, lq = tid & 31;
            float a0 = 0.f, a1 = 0.f, a2 = 0.f, a3 = 0.f;
            const unsigned long long* ub = (const unsigned long long*)U;
            const int nit = (nv + 7) >> 3;
            for (int it = 0; it < nit; ++it){
                int e = it*8 + w + lh*4;
                if (e < nv){
                    int pk = s2.list[e];
                    unsigned long long v = ld64c(ub + ((((pk & 511) << 6) | (pk >> 9)) << 5) + lq);
                    unsigned lo = (unsigned)v, hi = (unsigned)(v >> 32);
                    a0 += bf2lo(lo); a1 += bf2hi(lo);
                    a2 += bf2lo(hi); a3 += bf2hi(hi);
                }
            }
            { f32x4 sv = {a0, a1, a2, a3}; *(f32x4*)&s2.socp[w*2 + lh][lq*4] = sv; }
            __syncthreads();
            if (tid < 128){
                float s = b_p[tid];
                #pragma unroll
                for (int p = 0; p < 8; ++p) s += s2.socp[p][tid];
                if (!vi) s = 0.f;
                s2.x[64 + tid] = s;
            }
            __syncthreads();
            // LSTM matvec: thread (kh,u): 4 gate rows, K-half kh
            {
                const int kh = tid >> 7, u = tid & 127;
                float z0 = 0.f, z1 = 0.f, z2 = 0.f, z3 = 0.f;
                const uint4v* w0p = (const uint4v*)(wz + (      u)*K_CAT + kh*160);
                const uint4v* w1p = (const uint4v*)(wz + (128 + u)*K_CAT + kh*160);
                const uint4v* w2p = (const uint4v*)(wz + (256 + u)*K_CAT + kh*160);
                const uint4v* w3p = (const uint4v*)(wz + (384 + u)*K_CAT + kh*160);
                const float* xb = s2.x + kh*160;
                #pragma unroll 5
                for (int ck = 0; ck < 20; ++ck){
                    float xv[8];
                    #pragma unroll
                    for (int e = 0; e < 8; ++e) xv[e] = xb[ck*8 + e];
                    uint4v q0 = w0p[ck], q1 = w1p[ck], q2 = w2p[ck], q3 = w3p[ck];
                    #pragma unroll
                    for (int d = 0; d < 4; ++d){
                        z0 += bf2lo(q0[d])*xv[2*d] + bf2hi(q0[d])*xv[2*d+1];
                        z1 += bf2lo(q1[d])*xv[2*d] + bf2hi(q1[d])*xv[2*d+1];
                        z2 += bf2lo(q2[d])*xv[2*d] + bf2hi(q2[d])*xv[2*d+1];
                        z3 += bf2lo(q3[d])*xv[2*d] + bf2hi(q3[d])*xv[2*d+1];
                    }
                }
                s2.zpart[kh][      u] = z0;
                s2.zpart[kh][128 + u] = z1;
                s2.zpart[kh][256 + u] = z2;
                s2.zpart[kh][384 + u] = z3;
            }
            __syncthreads();
            if (tid < 128){
                float zi = s2.zpart[0][      tid] + s2.zpart[1][      tid] + bz[      tid];
                float zf = s2.zpart[0][128 + tid] + s2.zpart[1][128 + tid] + bz[128 + tid];
                float zg = s2.zpart[0][256 + tid] + s2.zpart[1][256 + tid] + bz[256 + tid];
                float zo = s2.zpart[0][384 + tid] + s2.zpart[1][384 + tid] + bz[384 + tid];
                float ig = sigm_f(zi), fg = sigm_f(zf);
                float gv = tanh_f(zg), og = sigm_f(zo);
                c_reg = fg * c_reg + ig * gv;
                h_reg = og * tanh_f(c_reg);
                s2.hrow[tid] = h_reg;
            }
            __syncthreads();
            if (tid < 64)
                st32c((unsigned*)hglob + bid*64 + tid,
                      pack2(s2.hrow[2*tid], s2.hrow[2*tid + 1]));
            if (t >= T_OBS && tid < 64){
                float h0 = s2.hrow[2*tid], h1 = s2.hrow[2*tid + 1];
                float p[5];
                #pragma unroll
                for (int o = 0; o < 5; ++o)
                    p[o] = W_o[o*128 + 2*tid]*h0 + W_o[o*128 + 2*tid + 1]*h1;
                #pragma unroll
                for (int s = 32; s; s >>= 1)
                    #pragma unroll
                    for (int o = 0; o < 5; ++o) p[o] += __shfl_xor(p[o], s, 64);
                if (tid == 0){
                    const int dec_t = t - T_OBS;
                    float mu0 = p[0] + b_o[0], mu1 = p[1] + b_o[1];
                    float s0 = __expf(p[2] + b_o[2]) + 1e-6f;
                    float s1 = __expf(p[3] + b_o[3]) + 1e-6f;
                    float rh = tanh_f(p[4] + b_o[4]);
                    if (t == T_OBS){ cx_r = pi.x; cy_r = pi.y; }   // cur0 (masked obs)
                    if (vi){ cx_r += mu0; cy_r += mu1; }
                    union { float f[2]; unsigned long long q; } cu;
                    cu.f[0] = cx_r; cu.f[1] = cy_r;
                    st64c((unsigned long long*)cur + bid, cu.q);
                    out[dec_t*1024 + bid*2]             = cx_r;
                    out[dec_t*1024 + bid*2 + 1]         = cy_r;
                    out[12288 + dec_t*1024 + bid*2]     = s0;
                    out[12288 + dec_t*1024 + bid*2 + 1] = s1;
                    out[24576 + dec_t*512 + bid]        = rh;
                }
            }
        }
        gridbar(bar, bid, gen);
    }
}

extern "C" void kernel_launch(void* const* d_in, const int* in_sizes, int n_in,
                              void* d_out, int out_size, void* d_ws, size_t ws_size,
                              hipStream_t stream)
{
    const float* obs  = (const float*)d_in[0];
    const unsigned char* mraw = (const unsigned char*)d_in[1];
    const float* W_e  = (const float*)d_in[2];
    const float* b_e  = (const float*)d_in[3];
    const float* W_p  = (const float*)d_in[4];
    const float* b_p  = (const float*)d_in[5];
    const float* W_ih = (const float*)d_in[6];
    const float* W_hh = (const float*)d_in[7];
    const float* b_ih = (const float*)d_in[8];
    const float* b_hh = (const float*)d_in[9];
    const float* W_o  = (const float*)d_in[10];
    const float* b_o  = (const float*)d_in[11];
    float* out = (float*)d_out;

    char* ws = (char*)d_ws;
    unsigned short* wp_bf = (unsigned short*)(ws + WP_OFF);
    unsigned short* wz_bf = (unsigned short*)(ws + WZ_OFF);
    float* bz   = (float*)(ws + BZ_OFF);
    int*   mski = (int*)  (ws + MASK_OFF);
    float* cur  = (float*)(ws + CUR_OFF);
    unsigned short* hglob = (unsigned short*)(ws + HG_OFF);
    unsigned short* U = (unsigned short*)(ws + U_OFF);
    int*   bar  = (int*)  (ws + BAR_OFF);

    bar_init<<<2, 1024, 0, stream>>>(bar);
    social_persist<<<NBLK, NTHR, 0, stream>>>(
        obs, mraw, W_e, b_e, W_p, b_p, W_ih, W_hh, b_ih, b_hh, W_o, b_o,
        wp_bf, wz_bf, bz, mski, cur, hglob, U, bar, out);
}

// Round 6
// 589.277 us; speedup vs baseline: 2.3178x; 2.3178x over previous
//
#include <hip/hip_runtime.h>

// Problem constants
#define A_N   512
#define E_DIM 64
#define H_DIM 128
#define K_CAT 320         // E + soc(128) + h(128)
#define T_OBS 8
#define PRED  12

typedef __attribute__((ext_vector_type(8))) short bf16x8;
typedef __attribute__((ext_vector_type(4))) float f32x4;
#define MFMA16(a,b,c) __builtin_amdgcn_mfma_f32_16x16x32_bf16((a),(b),(c),0,0,0)

// workspace offsets (bytes)
#define WP_OFF    0           // 128*8192*2 = 2097152
#define WZ_OFF    2097152     // 512*320*2  = 327680
#define BZ_OFF    2424832     // 512*4
#define MASK_OFF  2426880     // 512*4
#define CUR_OFF   2428928     // 512*2*4
#define XCAT0_OFF 2433024     // 512*320*2  = 327680
#define XCAT1_OFF 2760704     // 512*320*2  = 327680
#define CST_OFF   3088384     // 512*128*4  = 262144
#define U_OFF     3350528     // 512*64*128*2 = 8388608  -> ends 11739136

static __device__ __forceinline__ unsigned short f2bf(float x){
    union { float f; unsigned u; } v; v.f = x;
    unsigned r = v.u + 0x7fffu + ((v.u >> 16) & 1u);   // RNE
    return (unsigned short)(r >> 16);
}
static __device__ __forceinline__ unsigned pack2(float a, float b){
    return (unsigned)f2bf(a) | ((unsigned)f2bf(b) << 16);
}
static __device__ __forceinline__ float bf2lo(unsigned v){ return __uint_as_float(v << 16); }
static __device__ __forceinline__ float bf2hi(unsigned v){ return __uint_as_float(v & 0xffff0000u); }
static __device__ __forceinline__ float sigm_f(float x){ return 1.f / (1.f + __expf(-x)); }
static __device__ __forceinline__ float tanh_f(float x){
    float e = __expf(-2.f * fabsf(x));
    float t = (1.f - e) / (1.f + e);
    return copysignf(t, x);
}

// ---------------- prep: weights->bf16, zero h0/c0, mask decode ----------------
__global__ __launch_bounds__(256) void prep(
    const float* __restrict__ Wp, const float* __restrict__ Wih,
    const float* __restrict__ Whh, const float* __restrict__ bih,
    const float* __restrict__ bhh, const unsigned char* __restrict__ mraw,
    unsigned short* __restrict__ wp_bf, unsigned short* __restrict__ wz,
    float* __restrict__ bz, int* __restrict__ mski,
    unsigned* __restrict__ xc0_32, float* __restrict__ cst)
{
    __shared__ int mflagA, mflagB;
    const int bid = blockIdx.x, tid = threadIdx.x;
    const int i0 = bid * 256 + tid, stride = 512 * 256;
    for (int i = i0; i < 524288; i += stride)
        ((unsigned*)wp_bf)[i] = pack2(Wp[2*i], Wp[2*i + 1]);
    for (int i = i0; i < 81920; i += stride){
        int n = (2*i) / K_CAT, k = (2*i) - n*K_CAT;
        float w0 = (k < 192)     ? Wih[n*192 + k]     : Whh[n*128 + k - 192];
        float w1 = (k + 1 < 192) ? Wih[n*192 + k + 1] : Whh[n*128 + k + 1 - 192];
        ((unsigned*)wz)[i] = pack2(w0, w1);
    }
    for (int i = i0; i < 512; i += stride) bz[i] = bih[i] + bhh[i];
    for (int i = i0; i < 512*64; i += stride){         // xcat0 h-cols = 0 (bf16)
        int r = i >> 6, cc = i & 63;
        xc0_32[r*160 + 96 + cc] = 0u;
    }
    for (int i = i0; i < 512*128; i += stride) cst[i] = 0.f;
    if (bid == 0){
        if (tid == 0){ mflagA = 0; mflagB = 0; }
        __syncthreads();
        for (int j = tid; j < 512; j += 256){
            unsigned char b = mraw[j];
            if (b && (j & 3))        atomicAdd(&mflagA, 1);
            if (b && ((j & 7) == 4)) atomicAdd(&mflagB, 1);
        }
        __syncthreads();
        for (int j = tid; j < 512; j += 256){
            int v;
            if (mflagA)      v = mraw[j] ? 1 : 0;
            else if (mflagB) v = ((const int*)mraw)[j] ? 1 : 0;
            else             v = ((const long long*)mraw)[j] ? 1 : 0;
            mski[j] = v;
        }
    }
}

// ---------------- KU: decoder head (t-1) + U-GEMM -----------------------------
// U[j][c][n] = sum_k W_p[n, c*128+k] * h[j][k], h = bf16 cols 192.. of xcat[t&1]
// block (mq 0..15, cp 0..31): rows mq*32..+32, cells {2cp, 2cp+1}
__global__ __launch_bounds__(256) void ku(
    const unsigned short* __restrict__ xc,           // xcat[t&1] (h of t-1)
    const unsigned short* __restrict__ wp_bf,
    const float* __restrict__ obs, const float* __restrict__ W_o,
    const float* __restrict__ b_o, const int* __restrict__ mski,
    float* __restrict__ cur, float* __restrict__ out,
    unsigned short* __restrict__ U, int t)
{
    __shared__ unsigned short ustage[32][256];   // 16 KB
    const int bid = blockIdx.x, tid = threadIdx.x;

    // ---- decoder head for step t-1 (agent = bid) ----
    if (t > T_OBS && tid < 64){
        const int dec_t = t - T_OBS - 1;                 // 0..11
        unsigned v = ((const unsigned*)xc)[bid*160 + 96 + tid];
        float h0 = bf2lo(v), h1 = bf2hi(v);
        float p[5];
        #pragma unroll
        for (int o = 0; o < 5; ++o)
            p[o] = W_o[o*128 + 2*tid]*h0 + W_o[o*128 + 2*tid + 1]*h1;
        #pragma unroll
        for (int s = 32; s; s >>= 1)
            #pragma unroll
            for (int o = 0; o < 5; ++o) p[o] += __shfl_xor(p[o], s, 64);
        if (tid == 0){
            float mu0 = p[0] + b_o[0], mu1 = p[1] + b_o[1];
            float s0 = __expf(p[2] + b_o[2]) + 1e-6f;
            float s1 = __expf(p[3] + b_o[3]) + 1e-6f;
            float rh = tanh_f(p[4] + b_o[4]);
            float cx, cy;
            if (dec_t == 0){
                cx = obs[7*1024 + bid*2]; cy = obs[7*1024 + bid*2 + 1];
                if (isnan(cx)) cx = 0.f;
                if (isnan(cy)) cy = 0.f;
                if (!mski[bid]){ cx = 0.f; cy = 0.f; }
            } else {
                cx = cur[bid*2]; cy = cur[bid*2 + 1];
            }
            if (mski[bid]){ cx += mu0; cy += mu1; }
            cur[bid*2] = cx; cur[bid*2 + 1] = cy;
            out[dec_t*1024 + bid*2]             = cx;
            out[dec_t*1024 + bid*2 + 1]         = cy;
            out[12288 + dec_t*1024 + bid*2]     = s0;
            out[12288 + dec_t*1024 + bid*2 + 1] = s1;
            out[24576 + dec_t*512 + bid]        = rh;
        }
    }
    if (t >= T_OBS + PRED) return;    // tail launch: head only

    // ---- U-GEMM ----
    const int mq = bid >> 5, cp = bid & 31;
    const int r0 = mq * 32;
    const int w = tid >> 6, lane = tid & 63;
    const int msub = w & 1, nq = w >> 1;
    const int lrow = lane & 15, lk = (lane >> 4) * 8;
    f32x4 acc[2][4] = {};
    #pragma unroll
    for (int ks = 0; ks < 4; ++ks){
        bf16x8 a = *(const bf16x8*)(xc + (r0 + msub*16 + lrow)*K_CAT + 192 + ks*32 + lk);
        #pragma unroll
        for (int cell = 0; cell < 2; ++cell){
            #pragma unroll
            for (int ntl = 0; ntl < 4; ++ntl){
                const unsigned short* bp = wp_bf +
                    ((nq*4 + ntl)*16 + lrow)*8192 + (2*cp + cell)*128 + ks*32 + lk;
                acc[cell][ntl] = MFMA16(a, *(const bf16x8*)bp, acc[cell][ntl]);
            }
        }
    }
    const int crow = (lane >> 4) * 4, ccol = lane & 15;
    #pragma unroll
    for (int cell = 0; cell < 2; ++cell)
        #pragma unroll
        for (int ntl = 0; ntl < 4; ++ntl)
            #pragma unroll
            for (int r = 0; r < 4; ++r)
                ustage[msub*16 + crow + r][cell*128 + (nq*4 + ntl)*16 + ccol]
                    = f2bf(acc[cell][ntl][r]);
    __syncthreads();
    // flush 32 rows x 512B to U at ((r0+r)*64 + 2cp)*256
    for (int e = tid; e < 1024; e += 256){
        int r = e >> 5, o = e & 31;
        *(ulonglong2*)((char*)U + ((long long)(r0 + r)*64 + 2*cp)*256 + o*16)
            = *(const ulonglong2*)&ustage[r][o*8];
    }
}

// ---------------- KG: positions, cells, gather, soc, emb ----------------------
__global__ __launch_bounds__(256) void kg(
    const float* __restrict__ obs, const int* __restrict__ mski,
    const float* __restrict__ cur, const unsigned short* __restrict__ U,
    const float* __restrict__ W_e, const float* __restrict__ b_e,
    const float* __restrict__ b_p, unsigned* __restrict__ xc32, int t)
{
    __shared__ float2 pos_s[A_N];
    __shared__ short  cell_s[A_N];
    __shared__ short  list_s[A_N];
    __shared__ float  socp[8][128];
    __shared__ int    nvalid;
    const int bid = blockIdx.x, tid = threadIdx.x;
    const int mode = (t < T_OBS) ? 0 : ((t == T_OBS) ? 1 : 2);

    if (mode == 2){
        for (int j = tid; j < A_N; j += 256)
            pos_s[j] = make_float2(cur[j*2], cur[j*2 + 1]);
    } else {
        int tt = (mode == 0) ? t : (T_OBS - 1);
        for (int j = tid; j < A_N; j += 256){
            float px = obs[tt*1024 + 2*j], py = obs[tt*1024 + 2*j + 1];
            if (isnan(px)) px = 0.f;
            if (isnan(py)) py = 0.f;
            if (mode == 1 && !mski[j]){ px = 0.f; py = 0.f; }
            pos_s[j] = make_float2(px, py);
        }
    }
    __syncthreads();
    const float2 pi = pos_s[bid];
    const int vi = mski[bid];
    for (int j = tid; j < A_N; j += 256){
        int cc = -1;
        if (vi && j != bid && mski[j]){
            float rx = pos_s[j].x - pi.x, ry = pos_s[j].y - pi.y;
            if (fabsf(rx) < 32.f && fabsf(ry) < 32.f){
                int col = (int)floorf((rx + 32.f) * 0.125f);
                int row = (int)floorf((ry + 32.f) * 0.125f);
                col = min(max(col, 0), 7); row = min(max(row, 0), 7);
                cc = row*8 + col;
            }
        }
        cell_s[j] = (short)cc;
    }
    __syncthreads();
    if (tid < 64){
        int base = 0;
        for (int b = 0; b < 8; ++b){
            short cj = cell_s[b*64 + tid];
            bool val = cj >= 0;
            unsigned long long bal = __ballot(val);
            int pre = __popcll(bal & ((1ull << tid) - 1ull));
            if (val) list_s[base + pre] = (short)((b*64 + tid) | ((int)cj << 9));
            base += __popcll(bal);
        }
        if (tid == 0) nvalid = base;
    }
    __syncthreads();
    const int nv = nvalid;
    // gather: 8 entries per pass (4 waves x 2 half-waves, 8B/lane), unroll x4
    const int w = tid >> 6, lh = (tid >> 5) & 1, lq = tid & 31;
    const int e_off = w + lh*4;
    float a0 = 0.f, a1 = 0.f, a2 = 0.f, a3 = 0.f;
    const unsigned long long* ub = (const unsigned long long*)U;
    int b4 = 0;
    for (; b4 + 32 <= nv; b4 += 32){
        int p0 = list_s[b4      + e_off];
        int p1 = list_s[b4 + 8  + e_off];
        int p2 = list_s[b4 + 16 + e_off];
        int p3 = list_s[b4 + 24 + e_off];
        unsigned long long v0 = ub[((((p0 & 511) << 6) | (p0 >> 9)) << 5) + lq];
        unsigned long long v1 = ub[((((p1 & 511) << 6) | (p1 >> 9)) << 5) + lq];
        unsigned long long v2 = ub[((((p2 & 511) << 6) | (p2 >> 9)) << 5) + lq];
        unsigned long long v3 = ub[((((p3 & 511) << 6) | (p3 >> 9)) << 5) + lq];
        unsigned lo, hi;
        lo = (unsigned)v0; hi = (unsigned)(v0 >> 32);
        a0 += bf2lo(lo); a1 += bf2hi(lo); a2 += bf2lo(hi); a3 += bf2hi(hi);
        lo = (unsigned)v1; hi = (unsigned)(v1 >> 32);
        a0 += bf2lo(lo); a1 += bf2hi(lo); a2 += bf2lo(hi); a3 += bf2hi(hi);
        lo = (unsigned)v2; hi = (unsigned)(v2 >> 32);
        a0 += bf2lo(lo); a1 += bf2hi(lo); a2 += bf2lo(hi); a3 += bf2hi(hi);
        lo = (unsigned)v3; hi = (unsigned)(v3 >> 32);
        a0 += bf2lo(lo); a1 += bf2hi(lo); a2 += bf2lo(hi); a3 += bf2hi(hi);
    }
    for (; b4 < nv; b4 += 8){
        int e = b4 + e_off;
        if (e < nv){
            int pk = list_s[e];
            unsigned long long v = ub[((((pk & 511) << 6) | (pk >> 9)) << 5) + lq];
            unsigned lo = (unsigned)v, hi = (unsigned)(v >> 32);
            a0 += bf2lo(lo); a1 += bf2hi(lo); a2 += bf2lo(hi); a3 += bf2hi(hi);
        }
    }
    { f32x4 sv = {a0, a1, a2, a3}; *(f32x4*)&socp[w*2 + lh][lq*4] = sv; }
    __syncthreads();
    if (tid < 64){
        float s0 = b_p[2*tid], s1 = b_p[2*tid + 1];
        #pragma unroll
        for (int p = 0; p < 8; ++p){ s0 += socp[p][2*tid]; s1 += socp[p][2*tid + 1]; }
        if (!vi){ s0 = 0.f; s1 = 0.f; }
        xc32[bid*160 + 32 + tid] = pack2(s0, s1);
    } else if (tid < 96){
        int u = tid - 64;   // col pair
        float e0 = fmaxf(W_e[(2*u    )*2]*pi.x + W_e[(2*u    )*2 + 1]*pi.y + b_e[2*u    ], 0.f);
        float e1 = fmaxf(W_e[(2*u + 1)*2]*pi.x + W_e[(2*u + 1)*2 + 1]*pi.y + b_e[2*u + 1], 0.f);
        xc32[bid*160 + u] = pack2(e0, e1);
    }
}

// ---------------- KL: batched LSTM (128 blocks x 128 threads) -----------------
// block (rt 0..31, uq 0..3): rows rt*16..+16, units uq*32..+32
// wave w (0..1): units uq*32 + w*16 ..+16; all 4 gates of a unit in one lane.
__global__ __launch_bounds__(128) void kl(
    const unsigned short* __restrict__ xc,   // xcat[t&1]
    const unsigned short* __restrict__ wz, const float* __restrict__ bz,
    float* __restrict__ cst, unsigned* __restrict__ xcn32)   // xcat[(t+1)&1]
{
    __shared__ float hst[16][33];
    const int rt = blockIdx.x >> 2, uq = blockIdx.x & 3;
    const int tid = threadIdx.x;
    const int w = tid >> 6, lane = tid & 63;
    const int lrow = lane & 15, lk = (lane >> 4) * 8;
    const int r0 = rt * 16;

    f32x4 acc[4] = {};
    #pragma unroll
    for (int ks = 0; ks < 10; ++ks){
        bf16x8 a = *(const bf16x8*)(xc + (r0 + lrow)*K_CAT + ks*32 + lk);
        #pragma unroll
        for (int g = 0; g < 4; ++g){
            const unsigned short* bp = wz +
                (g*128 + uq*32 + w*16 + lrow)*K_CAT + ks*32 + lk;
            acc[g] = MFMA16(a, *(const bf16x8*)bp, acc[g]);
        }
    }
    const int crow = (lane >> 4) * 4;
    const int unit = uq*32 + w*16 + (lane & 15);
    const float bzi = bz[unit], bzf = bz[128 + unit];
    const float bzg = bz[256 + unit], bzo = bz[384 + unit];
    #pragma unroll
    for (int r = 0; r < 4; ++r){
        int row = crow + r;
        float zi = acc[0][r] + bzi;
        float zf = acc[1][r] + bzf;
        float zg = acc[2][r] + bzg;
        float zo = acc[3][r] + bzo;
        float ig = sigm_f(zi), fg = sigm_f(zf);
        float gv = tanh_f(zg), og = sigm_f(zo);
        int gi = (r0 + row)*H_DIM + unit;
        float cn = fg * cst[gi] + ig * gv;
        float hn = og * tanh_f(cn);
        cst[gi] = cn;
        hst[row][w*16 + (lane & 15)] = hn;
    }
    __syncthreads();
    for (int e = tid; e < 256; e += 128){
        int row = e >> 4, pp = e & 15;
        xcn32[(r0 + row)*160 + 96 + uq*16 + pp] = pack2(hst[row][2*pp], hst[row][2*pp + 1]);
    }
}

extern "C" void kernel_launch(void* const* d_in, const int* in_sizes, int n_in,
                              void* d_out, int out_size, void* d_ws, size_t ws_size,
                              hipStream_t stream)
{
    const float* obs  = (const float*)d_in[0];
    const unsigned char* mraw = (const unsigned char*)d_in[1];
    const float* W_e  = (const float*)d_in[2];
    const float* b_e  = (const float*)d_in[3];
    const float* W_p  = (const float*)d_in[4];
    const float* b_p  = (const float*)d_in[5];
    const float* W_ih = (const float*)d_in[6];
    const float* W_hh = (const float*)d_in[7];
    const float* b_ih = (const float*)d_in[8];
    const float* b_hh = (const float*)d_in[9];
    const float* W_o  = (const float*)d_in[10];
    const float* b_o  = (const float*)d_in[11];
    float* out = (float*)d_out;

    char* ws = (char*)d_ws;
    unsigned short* wp_bf = (unsigned short*)(ws + WP_OFF);
    unsigned short* wz_bf = (unsigned short*)(ws + WZ_OFF);
    float* bz   = (float*)(ws + BZ_OFF);
    int*   mski = (int*)  (ws + MASK_OFF);
    float* cur  = (float*)(ws + CUR_OFF);
    unsigned short* xcat[2] = { (unsigned short*)(ws + XCAT0_OFF),
                                (unsigned short*)(ws + XCAT1_OFF) };
    float* cst  = (float*)(ws + CST_OFF);
    unsigned short* U = (unsigned short*)(ws + U_OFF);

    prep<<<512, 256, 0, stream>>>(W_p, W_ih, W_hh, b_ih, b_hh, mraw,
                                  wp_bf, wz_bf, bz, mski,
                                  (unsigned*)xcat[0], cst);

    for (int t = 0; t < T_OBS + PRED; ++t){
        const unsigned short* xc = xcat[t & 1];
        unsigned short* xcn = xcat[(t + 1) & 1];
        ku<<<512, 256, 0, stream>>>(xc, wp_bf, obs, W_o, b_o, mski, cur, out, U, t);
        kg<<<512, 256, 0, stream>>>(obs, mski, cur, U, W_e, b_e, b_p,
                                    (unsigned*)xc, t);
        kl<<<128, 128, 0, stream>>>(xc, wz_bf, bz, cst, (unsigned*)xcn);
    }
    // tail: decoder head d = 11 from h(19) (in xcat[20&1] = xcat[0])
    ku<<<512, 256, 0, stream>>>(xcat[0], wp_bf, obs, W_o, b_o, mski, cur, out, U,
                                T_OBS + PRED);
}